// Round 8
// baseline (392.620 us; speedup 1.0000x reference)
//
#include <hip/hip_runtime.h>

typedef __attribute__((ext_vector_type(8))) short bf16x8;
typedef __attribute__((ext_vector_type(4))) float f32x4;
typedef __attribute__((ext_vector_type(4))) unsigned short u16x4;

#define DI __device__ __forceinline__

// Problem constants (B,S,D)=(2,2048,2048), H=16, KV=4, HD=128
constexpr int CB = 2, CS = 2048, CD = 2048, CH = 16, CKV = 4, CHD = 128;

DI unsigned short f2bf(float f) {
  unsigned u = __builtin_bit_cast(unsigned, f);
  u += 0x7fffu + ((u >> 16) & 1u);   // RNE
  return (unsigned short)(u >> 16);
}
DI float bf2f(unsigned short h) {
  return __builtin_bit_cast(float, (unsigned)h << 16);
}

// async global->LDS, 16B per lane; LDS dest = wave-uniform base + lane*16
#define GLOAD16(g, l) __builtin_amdgcn_global_load_lds(                      \
    (const __attribute__((address_space(1))) unsigned*)(g),                  \
    (__attribute__((address_space(3))) unsigned*)(l), 16, 0, 0)

// ---------------------------------------------------------------------------
// Flat f32 -> bf16 convert, 8 elems/thread.
// ---------------------------------------------------------------------------
__global__ __launch_bounds__(256) void cvt_bf16(const float* __restrict__ in,
                                                unsigned short* __restrict__ out)
{
  const size_t i = ((size_t)blockIdx.x * 256 + threadIdx.x) * 8;
  const float4 a = *(const float4*)&in[i];
  const float4 b = *(const float4*)&in[i + 4];
  bf16x8 v;
  v[0] = f2bf(a.x); v[1] = f2bf(a.y); v[2] = f2bf(a.z); v[3] = f2bf(a.w);
  v[4] = f2bf(b.x); v[5] = f2bf(b.y); v[6] = f2bf(b.z); v[7] = f2bf(b.w);
  *(bf16x8*)&out[i] = v;
}

// ---------------------------------------------------------------------------
// Transpose-convert: W [K][N] f32 -> Wt [N][K] bf16. 64x64 LDS tiles.
// ---------------------------------------------------------------------------
__global__ __launch_bounds__(256) void cvtT_bf16(const float* __restrict__ W,
                                                 unsigned short* __restrict__ Wt,
                                                 int K, int N)
{
  __shared__ __align__(16) unsigned short Ls[64][72];
  const int n0 = blockIdx.x * 64, k0 = blockIdx.y * 64;
  const int t = threadIdx.x;
  const int r = t >> 4, c = (t & 15) << 2;
#pragma unroll
  for (int ph = 0; ph < 4; ++ph) {
    const int row = ph * 16 + r;
    const float4 f = *(const float4*)&W[(size_t)(k0 + row) * N + n0 + c];
    Ls[c + 0][row] = f2bf(f.x);
    Ls[c + 1][row] = f2bf(f.y);
    Ls[c + 2][row] = f2bf(f.z);
    Ls[c + 3][row] = f2bf(f.w);
  }
  __syncthreads();
  const int wr = t >> 2, wc = (t & 3) << 4;
  const bf16x8 v0 = *(const bf16x8*)&Ls[wr][wc];
  const bf16x8 v1 = *(const bf16x8*)&Ls[wr][wc + 8];
  *(bf16x8*)&Wt[(size_t)(n0 + wr) * K + k0 + wc]     = v0;
  *(bf16x8*)&Wt[(size_t)(n0 + wr) * K + k0 + wc + 8] = v1;
}

// ---------------------------------------------------------------------------
// m97-style GEMM with XCD-aware block swizzle (T1; nwg % 8 == 0 required).
// MODE 0: C f32. MODE 2: fused QKV split (boundaries 128-aligned).
// ---------------------------------------------------------------------------
template <int MODE>
__global__ __launch_bounds__(256) void gemm_bt(
    const unsigned short* __restrict__ A, const unsigned short* __restrict__ Bt,
    void* __restrict__ Cptr, unsigned short* __restrict__ K2,
    unsigned short* __restrict__ V2, int M, int N, int K)
{
  __shared__ __align__(16) unsigned short As[128 * 32];
  __shared__ __align__(16) unsigned short Bs[128 * 32];

  const int t = threadIdx.x;
  const int w = t >> 6, l = t & 63;
  const int l15 = l & 15, lg = l >> 4;
  const int wr = w >> 1, wc = w & 1;

  // XCD swizzle: contiguous chunk of blocks per XCD (bijective since nwg%8==0)
  const int gx = gridDim.x;
  int lid = blockIdx.x + gx * blockIdx.y;
  const int cpx = (gx * gridDim.y) >> 3;
  lid = (lid & 7) * cpx + (lid >> 3);
  const int m0 = (lid / gx) * 128;
  const int n0 = (lid % gx) * 128;

  const int sr = l >> 2, sc = (l & 3) << 3;
  const unsigned short* aSrc0 = A  + (size_t)(m0 + w * 16 + sr) * K + sc;
  const unsigned short* aSrc1 = A  + (size_t)(m0 + 64 + w * 16 + sr) * K + sc;
  const unsigned short* bSrc0 = Bt + (size_t)(n0 + w * 16 + sr) * K + sc;
  const unsigned short* bSrc1 = Bt + (size_t)(n0 + 64 + w * 16 + sr) * K + sc;
  unsigned short* aDst0 = As + (w * 16) * 32;
  unsigned short* aDst1 = As + (64 + w * 16) * 32;
  unsigned short* bDst0 = Bs + (w * 16) * 32;
  unsigned short* bDst1 = Bs + (64 + w * 16) * 32;

  f32x4 acc[4][4];
#pragma unroll
  for (int i = 0; i < 4; ++i)
#pragma unroll
    for (int j = 0; j < 4; ++j) acc[i][j] = (f32x4){0.f, 0.f, 0.f, 0.f};

  for (int kt = 0; kt < K; kt += 32) {
    GLOAD16(aSrc0 + kt, aDst0);
    GLOAD16(aSrc1 + kt, aDst1);
    GLOAD16(bSrc0 + kt, bDst0);
    GLOAD16(bSrc1 + kt, bDst1);
    __syncthreads();

    bf16x8 aF[4], bF[4];
#pragma unroll
    for (int i = 0; i < 4; ++i) {
      aF[i] = *(const bf16x8*)&As[(wr * 64 + i * 16 + l15) * 32 + lg * 8];
      bF[i] = *(const bf16x8*)&Bs[(wc * 64 + i * 16 + l15) * 32 + lg * 8];
    }
#pragma unroll
    for (int mi = 0; mi < 4; ++mi)
#pragma unroll
      for (int ni = 0; ni < 4; ++ni)
        acc[mi][ni] = __builtin_amdgcn_mfma_f32_16x16x32_bf16(aF[mi], bF[ni], acc[mi][ni], 0, 0, 0);

    __syncthreads();
  }

  unsigned short* dst16 = nullptr;
  int cstr = N, coff = n0;
  if (MODE == 2) {
    if (n0 < 2048)      { dst16 = (unsigned short*)Cptr; cstr = 2048; coff = n0; }
    else if (n0 < 2560) { dst16 = K2; cstr = 512; coff = n0 - 2048; }
    else                { dst16 = V2; cstr = 512; coff = n0 - 2560; }
  }
#pragma unroll
  for (int mi = 0; mi < 4; ++mi) {
    const int row0 = m0 + wr * 64 + mi * 16 + lg * 4;
#pragma unroll
    for (int j = 0; j < 4; ++j) {
#pragma unroll
      for (int ni = 0; ni < 4; ++ni) {
        const int cl = wc * 64 + ni * 16 + l15;
        const float v = acc[mi][ni][j];
        if (MODE == 0)
          ((float*)Cptr)[(size_t)(row0 + j) * N + n0 + cl] = v;
        else
          dst16[(size_t)(row0 + j) * cstr + coff + cl] = f2bf(v);
      }
    }
  }
}

// ---------------------------------------------------------------------------
// RoPE in-place on bf16 [B][S][nH][128]; scale folds 1/sqrt(HD) into Q.
// ---------------------------------------------------------------------------
__global__ void rope_bf16(unsigned short* __restrict__ tq,
                          const float* __restrict__ cosT,
                          const float* __restrict__ sinT,
                          int nH, float scale, int total)
{
  int idx = blockIdx.x * blockDim.x + threadIdx.x;
  if (idx >= total) return;
  const int p    = idx & 63;
  const int rest = idx >> 6;
  const int s    = (rest / nH) & (CS - 1);
  const float c  = cosT[s * 64 + p];
  const float sn = sinT[s * 64 + p];
  unsigned short* ptr = tq + (size_t)rest * CHD;
  const unsigned pair = *(const unsigned*)&ptr[2 * p];
  const float re = bf2f((unsigned short)pair);
  const float im = bf2f((unsigned short)(pair >> 16));
  const unsigned short lo = f2bf((re * c - im * sn) * scale);
  const unsigned short hi = f2bf((re * sn + im * c) * scale);
  *(unsigned*)&ptr[2 * p] = (unsigned)lo | ((unsigned)hi << 16);
}

// ---------------------------------------------------------------------------
// MFMA causal GQA flash attention. 4 waves x 32 q-rows = 128-row q-tile.
// Block g handles q-tiles g and 15-g (uniform 34 K-tiles). Per K-tile, each
// wave: 64 MFMA over two independent 16-row fragments; K/V frag reads and
// staging amortized over 2x rows vs round 6. T14 prefetch + T5 setprio.
// LDS: K [64][136], Vt [128][72], P [4][32][72]  = 53 KB.
// ---------------------------------------------------------------------------
__global__ __launch_bounds__(256) void attn_mfma(
    const unsigned short* __restrict__ Qb, const unsigned short* __restrict__ Kb,
    const unsigned short* __restrict__ Vb, unsigned short* __restrict__ Ob)
{
  constexpr int KSTR = 136, VSTR = 72, PSTR = 72, NT = CS / 128;  // 16
  __shared__ __align__(16) unsigned short KsB[64 * KSTR];
  __shared__ __align__(16) unsigned short VtB[128 * VSTR];
  __shared__ __align__(16) unsigned short PsB[4 * 32 * PSTR];

  const int t   = threadIdx.x;
  const int w   = t >> 6, l = t & 63;
  const int l15 = l & 15, lg = l >> 4;
  const int g = blockIdx.x, h = blockIdx.y, b = blockIdx.z;
  const int kvh = h >> 2;

  const int skr = t >> 2, skc = (t & 3) << 5;

  bf16x8 kpre[4];
  u16x4  vpre0[4], vpre1[4];

#define ATTN_PREFETCH(KT)                                                          \
  {                                                                                \
    const unsigned short* ksrc =                                                   \
        Kb + ((size_t)(b * CS + (KT) + skr) * CKV + kvh) * CHD + skc;              \
    _Pragma("unroll") for (int i = 0; i < 4; ++i)                                  \
        kpre[i] = *(const bf16x8*)&ksrc[i * 8];                                    \
    _Pragma("unroll") for (int ii = 0; ii < 4; ++ii) {                             \
      const int idx = t + 256 * ii;                                                \
      const int kp = idx & 31, dg = idx >> 5;                                      \
      const unsigned short* vsrc =                                                 \
          Vb + ((size_t)(b * CS + (KT) + kp * 2) * CKV + kvh) * CHD + dg * 4;      \
      vpre0[ii] = *(const u16x4*)vsrc;                                             \
      vpre1[ii] = *(const u16x4*)(vsrc + (size_t)CKV * CHD);                       \
    }                                                                              \
  }

#define ATTN_WRITE_LDS                                                             \
  {                                                                                \
    _Pragma("unroll") for (int i = 0; i < 4; ++i)                                  \
        *(bf16x8*)&KsB[skr * KSTR + skc + i * 8] = kpre[i];                        \
    _Pragma("unroll") for (int ii = 0; ii < 4; ++ii) {                             \
      const int idx = t + 256 * ii;                                                \
      const int kp = idx & 31, dg = idx >> 5;                                      \
      const int r = kp * 2;                                                        \
      _Pragma("unroll") for (int c2 = 0; c2 < 4; ++c2)                             \
        *(unsigned*)&VtB[(dg * 4 + c2) * VSTR + r] =                               \
            (unsigned)(unsigned short)vpre0[ii][c2] |                              \
            ((unsigned)(unsigned short)vpre1[ii][c2] << 16);                       \
    }                                                                              \
  }

#pragma unroll 1
  for (int qi = 0; qi < 2; ++qi) {
    const int qt = qi ? (NT - 1 - g) : g;
    const int q0 = qt * 128;
    const int last = q0 + 64;          // last K-tile start (keys up to q0+127)

    // Q frags: 2 row-fragments x 4 k-slices, direct from global
    bf16x8 qf[2][4];
#pragma unroll
    for (int rt = 0; rt < 2; ++rt) {
      const size_t qrow = ((size_t)(b * CS + q0 + w * 32 + rt * 16 + l15) * CH + h) * CHD;
#pragma unroll
      for (int kk = 0; kk < 4; ++kk)
        qf[rt][kk] = *(const bf16x8*)&Qb[qrow + kk * 32 + lg * 8];
    }

    f32x4 accO[2][8];
#pragma unroll
    for (int rt = 0; rt < 2; ++rt)
#pragma unroll
      for (int i = 0; i < 8; ++i) accO[rt][i] = (f32x4){0.f, 0.f, 0.f, 0.f};
    float m_j[2][4], l_j[2][4];
#pragma unroll
    for (int rt = 0; rt < 2; ++rt)
#pragma unroll
      for (int j = 0; j < 4; ++j) { m_j[rt][j] = -1e30f; l_j[rt][j] = 0.f; }

    ATTN_PREFETCH(0);

    for (int kt = 0; kt <= last; kt += 64) {
      __syncthreads();             // all waves' LDS reads of prev tile done
      ATTN_WRITE_LDS;
      if (kt + 64 <= last) ATTN_PREFETCH(kt + 64);
      __syncthreads();             // tiles visible

      unsigned short* Pw = PsB + w * 32 * PSTR;

#pragma unroll
      for (int rt = 0; rt < 2; ++rt) {
        // ---- QK^T: S(16x64) for this row-fragment
        f32x4 s[4];
#pragma unroll
        for (int ks = 0; ks < 4; ++ks) s[ks] = (f32x4){0.f, 0.f, 0.f, 0.f};
        __builtin_amdgcn_s_setprio(1);
#pragma unroll
        for (int kk = 0; kk < 4; ++kk)
#pragma unroll
          for (int ks = 0; ks < 4; ++ks) {
            const bf16x8 bf = *(const bf16x8*)&KsB[(ks * 16 + l15) * KSTR + kk * 32 + lg * 8];
            s[ks] = __builtin_amdgcn_mfma_f32_16x16x32_bf16(qf[rt][kk], bf, s[ks], 0, 0, 0);
          }
        __builtin_amdgcn_s_setprio(0);

        // ---- causal mask (only the two diagonal-region tiles)
        if (kt + 64 > q0) {
          const int qr = q0 + w * 32 + rt * 16 + lg * 4;
#pragma unroll
          for (int ks = 0; ks < 4; ++ks) {
            const int kg = kt + ks * 16 + l15;
#pragma unroll
            for (int j = 0; j < 4; ++j)
              if (kg > qr + j) s[ks][j] = -1e30f;
          }
        }

        // ---- online softmax (16-lane-group reduce, 4 rows/lane)
        float rs[4];
#pragma unroll
        for (int j = 0; j < 4; ++j) {
          float mx = fmaxf(fmaxf(s[0][j], s[1][j]), fmaxf(s[2][j], s[3][j]));
          mx = fmaxf(mx, __shfl_xor(mx, 1));
          mx = fmaxf(mx, __shfl_xor(mx, 2));
          mx = fmaxf(mx, __shfl_xor(mx, 4));
          mx = fmaxf(mx, __shfl_xor(mx, 8));
          const float mnew = fmaxf(m_j[rt][j], mx);
          float sum = 0.f;
#pragma unroll
          for (int ks = 0; ks < 4; ++ks) {
            const float p = __expf(s[ks][j] - mnew);
            s[ks][j] = p;
            sum += p;
          }
          sum += __shfl_xor(sum, 1);
          sum += __shfl_xor(sum, 2);
          sum += __shfl_xor(sum, 4);
          sum += __shfl_xor(sum, 8);
          rs[j]      = __expf(m_j[rt][j] - mnew);
          l_j[rt][j] = l_j[rt][j] * rs[j] + sum;
          m_j[rt][j] = mnew;
        }
#pragma unroll
        for (int d8 = 0; d8 < 8; ++d8)
#pragma unroll
          for (int j = 0; j < 4; ++j) accO[rt][d8][j] *= rs[j];

        // ---- P (C-layout) -> per-wave LDS bf16, rows rt*16 + lg*4+j
#pragma unroll
        for (int ks = 0; ks < 4; ++ks)
#pragma unroll
          for (int j = 0; j < 4; ++j)
            Pw[(rt * 16 + lg * 4 + j) * PSTR + ks * 16 + l15] = f2bf(s[ks][j]);
      }

      // ---- PV: O(32x128) += P(32x64) @ V(64x128); V frags shared across rt
      __builtin_amdgcn_s_setprio(1);
#pragma unroll
      for (int k2 = 0; k2 < 2; ++k2) {
        const bf16x8 pa0 = *(const bf16x8*)&Pw[(l15) * PSTR + k2 * 32 + lg * 8];
        const bf16x8 pa1 = *(const bf16x8*)&Pw[(16 + l15) * PSTR + k2 * 32 + lg * 8];
#pragma unroll
        for (int d8 = 0; d8 < 8; ++d8) {
          const bf16x8 bv = *(const bf16x8*)&VtB[(d8 * 16 + l15) * VSTR + k2 * 32 + lg * 8];
          accO[0][d8] = __builtin_amdgcn_mfma_f32_16x16x32_bf16(pa0, bv, accO[0][d8], 0, 0, 0);
          accO[1][d8] = __builtin_amdgcn_mfma_f32_16x16x32_bf16(pa1, bv, accO[1][d8], 0, 0, 0);
        }
      }
      __builtin_amdgcn_s_setprio(0);
    }

    // ---- epilogue: normalize, store bf16 (in-place over Qb; rows exclusive)
#pragma unroll
    for (int rt = 0; rt < 2; ++rt)
#pragma unroll
      for (int j = 0; j < 4; ++j) {
        const float inv = 1.f / l_j[rt][j];
        const size_t base =
            ((size_t)(b * CS + q0 + w * 32 + rt * 16 + lg * 4 + j) * CH + h) * CHD;
#pragma unroll
        for (int d8 = 0; d8 < 8; ++d8)
          Ob[base + d8 * 16 + l15] = f2bf(accO[rt][d8][j] * inv);
      }
  }
#undef ATTN_PREFETCH
#undef ATTN_WRITE_LDS
}

// ---------------------------------------------------------------------------
extern "C" void kernel_launch(void* const* d_in, const int* in_sizes, int n_in,
                              void* d_out, int out_size, void* d_ws, size_t ws_size,
                              hipStream_t stream)
{
  const float* x  = (const float*)d_in[0];
  const float* wq = (const float*)d_in[1];
  const float* wk = (const float*)d_in[2];
  const float* wv = (const float*)d_in[3];
  const float* wo = (const float*)d_in[4];
  const float* fc = (const float*)d_in[5];
  const float* fs = (const float*)d_in[6];
  float* out = (float*)d_out;

  // ws (bf16): qb 8.4M | kb 2.1M | vb 2.1M | wt 6.3M  = 37.8 MB
  // xb (bf16 x, 16.8 MB) lives in d_out — dead before the final GEMM writes it.
  unsigned short* qb = (unsigned short*)d_ws;
  unsigned short* kb = qb + (size_t)CB * CS * CH * CHD;
  unsigned short* vb = kb + (size_t)CB * CS * CKV * CHD;
  unsigned short* wt = vb + (size_t)CB * CS * CKV * CHD;
  unsigned short* xb = (unsigned short*)d_out;

  const int M = CB * CS;  // 4096
  dim3 blk(256);

  cvt_bf16<<<dim3((CB * CS * CD) / (256 * 8)), blk, 0, stream>>>(x, xb);

  cvtT_bf16<<<dim3(CD / 64, CD / 64), blk, 0, stream>>>(wq, wt, CD, CD);
  cvtT_bf16<<<dim3((CKV * CHD) / 64, CD / 64), blk, 0, stream>>>(wk, wt + (size_t)2048 * CD, CD, CKV * CHD);
  cvtT_bf16<<<dim3((CKV * CHD) / 64, CD / 64), blk, 0, stream>>>(wv, wt + (size_t)2560 * CD, CD, CKV * CHD);

  gemm_bt<2><<<dim3(3072 / 128, M / 128), blk, 0, stream>>>(xb, wt, qb, kb, vb, M, 3072, CD);

  const int qpairs = CB * CS * CH * (CHD / 2);
  const int kpairs = CB * CS * CKV * (CHD / 2);
  rope_bf16<<<(qpairs + 255) / 256, 256, 0, stream>>>(qb, fc, fs, CH, 0.08838834764831845f, qpairs);
  rope_bf16<<<(kpairs + 255) / 256, 256, 0, stream>>>(kb, fc, fs, CKV, 1.0f, kpairs);

  attn_mfma<<<dim3(CS / 256, CH, CB), blk, 0, stream>>>(qb, kb, vb, qb);

  cvtT_bf16<<<dim3(CD / 64, CD / 64), blk, 0, stream>>>(wo, wt, CD, CD);
  gemm_bt<0><<<dim3(CD / 128, M / 128), blk, 0, stream>>>(qb, wt, out, nullptr, nullptr, M, CD, CD);
}